// Round 1
// baseline (718.573 us; speedup 1.0000x reference)
//
#include <hip/hip_runtime.h>

// TopKRouter: B=4, S=8192, D=2048, E=64, K=2. N = 32768 tokens.
// Outputs (flat float32, concatenated):
//   [0      .. 65535 ] expert_indices  (as floats)
//   [65536  .. 131071] expert_weights
//   [131072 .. 131135] expert_counts
//   [131136]           capacity_overflow_pct
//   [131137]           z_loss
//   [131138]           gate_entropy
//   [131139]           expert_load_variance
//   [131140 .. 163907] routing_confidence

#define NTOK 32768
#define DDIM 2048
#define NEXP 64
#define TTILE 64
#define KC 64
#define NCHUNK (DDIM / KC)

#define OFF_IDX 0
#define OFF_W 65536
#define OFF_CNT 131072
#define OFF_OVF 131136
#define OFF_ZL 131137
#define OFF_ENT 131138
#define OFF_VAR 131139
#define OFF_CONF 131140

struct RouterWS {
  unsigned int counts[NEXP];  // 256 B
  double z_sum;               // offset 256, aligned
  double ent_sum;
};

__global__ __launch_bounds__(256, 2) void router_main(
    const float* __restrict__ x, const float* __restrict__ w,
    float* __restrict__ out, RouterWS* __restrict__ ws) {
  // Swizzled fp32 tiles: element [r][c] stored at r*KC + (c ^ ((r>>2 & 7)<<2)).
  __shared__ float xs[TTILE * KC];
  __shared__ float wsh[NEXP * KC];
  __shared__ float lg[TTILE * 65];  // logits, stride 65 to break bank aliasing
  __shared__ unsigned int hist[NEXP];

  const int tid = threadIdx.x;
  const int col4 = tid & 15;  // loader: which float4 column (0..15)
  const int r0 = tid >> 4;    // loader: base row (0..15), rows r0+16*i
  const int ty = tid >> 4;    // compute: token group (4 tokens each)
  const int tx = tid & 15;    // compute: expert group (4 experts each)
  const int sx = (ty & 7) << 2;  // read-swizzle for x rows 4*ty+i (i<4 => row>>2 == ty)
  const int sw = (tx & 7) << 2;  // read-swizzle for w rows 4*tx+j

  const float* xg = x + (size_t)blockIdx.x * TTILE * DDIM;

  // Prefetch chunk 0 into registers.
  float4 rx[4], rw[4];
#pragma unroll
  for (int i = 0; i < 4; ++i) {
    int r = r0 + 16 * i;
    rx[i] = *(const float4*)(xg + (size_t)r * DDIM + col4 * 4);
    rw[i] = *(const float4*)(w + (size_t)r * DDIM + col4 * 4);
  }

  float acc[4][4];
#pragma unroll
  for (int i = 0; i < 4; ++i)
#pragma unroll
    for (int j = 0; j < 4; ++j) acc[i][j] = 0.f;

  for (int c = 0; c < NCHUNK; ++c) {
    __syncthreads();  // previous chunk's compute done; LDS safe to overwrite
#pragma unroll
    for (int i = 0; i < 4; ++i) {
      int r = r0 + 16 * i;
      int cs = (col4 * 4) ^ (((r >> 2) & 7) << 2);
      *(float4*)&xs[r * KC + cs] = rx[i];
      *(float4*)&wsh[r * KC + cs] = rw[i];
    }
    __syncthreads();
    if (c + 1 < NCHUNK) {  // prefetch next chunk; latency hides under compute
      int koff = (c + 1) * KC;
#pragma unroll
      for (int i = 0; i < 4; ++i) {
        int r = r0 + 16 * i;
        rx[i] = *(const float4*)(xg + (size_t)r * DDIM + koff + col4 * 4);
        rw[i] = *(const float4*)(w + (size_t)r * DDIM + koff + col4 * 4);
      }
    }
#pragma unroll
    for (int k4 = 0; k4 < 16; ++k4) {
      int k = k4 * 4;
      float4 a[4], b[4];
#pragma unroll
      for (int i = 0; i < 4; ++i)
        a[i] = *(const float4*)&xs[(4 * ty + i) * KC + (k ^ sx)];
#pragma unroll
      for (int j = 0; j < 4; ++j)
        b[j] = *(const float4*)&wsh[(4 * tx + j) * KC + (k ^ sw)];
#pragma unroll
      for (int i = 0; i < 4; ++i)
#pragma unroll
        for (int j = 0; j < 4; ++j)
          acc[i][j] += a[i].x * b[j].x + a[i].y * b[j].y +
                       a[i].z * b[j].z + a[i].w * b[j].w;
    }
  }

  // Scatter logits to LDS for the per-token tail.
#pragma unroll
  for (int i = 0; i < 4; ++i)
#pragma unroll
    for (int j = 0; j < 4; ++j)
      lg[(4 * ty + i) * 65 + 4 * tx + j] = acc[i][j];

  if (tid < NEXP) hist[tid] = 0;
  __syncthreads();

  if (tid < NEXP) {  // wave 0: one token per lane, serial over 64 experts
    const int t = tid;
    const float* L = &lg[t * 65];

    // top-1: strict > keeps the LOWEST index on ties (matches lax.top_k)
    float m1 = L[0];
    int i1 = 0;
    for (int e = 1; e < NEXP; ++e) {
      float v = L[e];
      if (v > m1) { m1 = v; i1 = e; }
    }
    // top-2 among the rest, again lowest index on ties
    float m2 = -3.4e38f;
    int i2 = 0;
    for (int e = 0; e < NEXP; ++e) {
      if (e == i1) continue;
      float v = L[e];
      if (v > m2) { m2 = v; i2 = e; }
    }

    float s = 0.f;
    for (int e = 0; e < NEXP; ++e) s += expf(L[e] - m1);
    float p1 = expf(L[i1] - m1) / s;
    float p2 = expf(L[i2] - m1) / s;
    float wsum = p1 + p2 + 1e-8f;
    float w1 = p1 / wsum;
    float w2 = p2 / wsum;

    float ent = 0.f;
    for (int e = 0; e < NEXP; ++e) {
      float p = expf(L[e] - m1) / s;
      ent -= p * logf(p + 1e-10f);
    }
    float lse = m1 + logf(s);

    size_t gt = (size_t)blockIdx.x * TTILE + t;
    out[OFF_IDX + gt * 2 + 0] = (float)i1;
    out[OFF_IDX + gt * 2 + 1] = (float)i2;
    out[OFF_W + gt * 2 + 0] = w1;
    out[OFF_W + gt * 2 + 1] = w2;
    out[OFF_CONF + gt] = fmaxf(w1, w2);

    atomicAdd(&hist[i1], 1u);
    atomicAdd(&hist[i2], 1u);

    // wave-reduce z / entropy sums, one double-atomic per block
    float zv = lse, ev = ent;
#pragma unroll
    for (int o = 32; o > 0; o >>= 1) {
      zv += __shfl_down(zv, o);
      ev += __shfl_down(ev, o);
    }
    if (t == 0) {
      atomicAdd(&ws->z_sum, (double)zv);
      atomicAdd(&ws->ent_sum, (double)ev);
    }
  }
  __syncthreads();
  if (tid < NEXP) atomicAdd(&ws->counts[tid], hist[tid]);
}

__global__ void router_final(float* __restrict__ out, RouterWS* __restrict__ ws) {
  int e = threadIdx.x;  // 64 threads
  float c = (float)ws->counts[e];
  out[OFF_CNT + e] = c;
  float over = fmaxf(c - 1280.f, 0.f);             // capacity = int(1.25*32768/64*2)
  float ld = c / 65536.f - (1.f / 64.f);           // counts sum is exactly 65536
  float so = over, sv = ld * ld;
#pragma unroll
  for (int o = 32; o > 0; o >>= 1) {
    so += __shfl_down(so, o);
    sv += __shfl_down(sv, o);
  }
  if (e == 0) {
    out[OFF_OVF] = so / 32768.f * 100.f;
    out[OFF_VAR] = sv / 64.f;
    out[OFF_ZL] = (float)(ws->z_sum / 32768.0 * 0.01);
    out[OFF_ENT] = (float)(ws->ent_sum / 32768.0);
  }
}

extern "C" void kernel_launch(void* const* d_in, const int* in_sizes, int n_in,
                              void* d_out, int out_size, void* d_ws, size_t ws_size,
                              hipStream_t stream) {
  const float* x = (const float*)d_in[0];   // hidden_states [4,8192,2048] f32
  const float* w = (const float*)d_in[1];   // gate_weight [64,2048] f32
  float* out = (float*)d_out;
  RouterWS* ws = (RouterWS*)d_ws;

  hipMemsetAsync(d_ws, 0, sizeof(RouterWS), stream);  // atomics must start at 0 every call
  hipLaunchKernelGGL(router_main, dim3(NTOK / TTILE), dim3(256), 0, stream,
                     x, w, out, ws);
  hipLaunchKernelGGL(router_final, dim3(1), dim3(64), 0, stream, out, ws);
}

// Round 2
// 336.012 us; speedup vs baseline: 2.1385x; 2.1385x over previous
//
#include <hip/hip_runtime.h>

// TopKRouter: N=32768 tokens, D=2048, E=64, K=2.
// R2: scalar-broadcast GEMM. Wave-uniform w via s_load (SGPR operand in
// v_fmac), per-lane token x in VGPRs. LDS only stages x (1:64 LDS:FMA ratio).

#define NTOK 32768
#define DDIM 2048
#define NEXP 64
#define TTILE 64          // tokens per block
#define KB 32             // k-chunk
#define NCH (DDIM / KB)   // 64
#define XS_STRIDE 36      // 32 + 4 pad: spreads per-row b128 reads over banks
#define LG_STRIDE 68      // 64 + 4 pad for logit tail

#define OFF_IDX 0
#define OFF_W 65536
#define OFF_CNT 131072
#define OFF_OVF 131136
#define OFF_ZL 131137
#define OFF_ENT 131138
#define OFF_VAR 131139
#define OFF_CONF 131140

struct RouterWS {
  unsigned int counts[NEXP];
  double z_sum;
  double ent_sum;
};

__global__ __launch_bounds__(256, 2) void router_main(
    const float* __restrict__ x, const float* __restrict__ w,
    float* __restrict__ out, RouterWS* __restrict__ ws) {
  // smem serves as xs[64][36] during GEMM, then lg[64][68] for the tail.
  __shared__ float smem[TTILE * LG_STRIDE];
  __shared__ unsigned int hist[NEXP];

  const int tid = threadIdx.x;
  const int lane = tid & 63;                                   // token-in-block
  const int wv = __builtin_amdgcn_readfirstlane(tid >> 6);     // expert group, forced scalar

  const float* xg = x + (size_t)blockIdx.x * TTILE * DDIM;

  // staging map: 512 float4 per chunk, 2 per thread
  const int row0 = tid >> 3;        // v=0 rows 0..31
  const int row1 = row0 + 32;       // v=1 rows 32..63
  const int c4 = tid & 7;           // float4 column within chunk

  float4 rx0, rx1;
  rx0 = *(const float4*)(xg + (size_t)row0 * DDIM + c4 * 4);
  rx1 = *(const float4*)(xg + (size_t)row1 * DDIM + c4 * 4);

  float acc[16];
#pragma unroll
  for (int e = 0; e < 16; ++e) acc[e] = 0.f;

  const float* wbase = w + (size_t)wv * 16 * DDIM;

  for (int c = 0; c < NCH; ++c) {
    if (c) __syncthreads();  // previous chunk's LDS reads complete
    *(float4*)&smem[row0 * XS_STRIDE + c4 * 4] = rx0;
    *(float4*)&smem[row1 * XS_STRIDE + c4 * 4] = rx1;
    __syncthreads();
    if (c + 1 < NCH) {  // prefetch next chunk; overlaps FMA work below
      int k0 = (c + 1) * KB;
      rx0 = *(const float4*)(xg + (size_t)row0 * DDIM + k0 + c4 * 4);
      rx1 = *(const float4*)(xg + (size_t)row1 * DDIM + k0 + c4 * 4);
    }

    // my token's 32 x-values -> VGPRs (8 ds_read_b128, reused by 16 experts)
    float xr[KB];
#pragma unroll
    for (int m = 0; m < 8; ++m)
      *(float4*)&xr[4 * m] = *(const float4*)&smem[lane * XS_STRIDE + 4 * m];

    const float* wc = wbase + c * KB;
#pragma unroll
    for (int e = 0; e < 16; ++e) {
      const float4* we = (const float4*)(wc + (size_t)e * DDIM);  // uniform -> s_load
      float a = acc[e];
#pragma unroll
      for (int m = 0; m < 8; ++m) {
        float4 wq = we[m];
        a = fmaf(xr[4 * m + 0], wq.x, a);
        a = fmaf(xr[4 * m + 1], wq.y, a);
        a = fmaf(xr[4 * m + 2], wq.z, a);
        a = fmaf(xr[4 * m + 3], wq.w, a);
      }
      acc[e] = a;
    }
  }

  // logits -> smem as lg[token][expert], stride 68
  __syncthreads();
#pragma unroll
  for (int m = 0; m < 4; ++m)
    *(float4*)&smem[lane * LG_STRIDE + wv * 16 + 4 * m] = *(float4*)&acc[4 * m];
  if (tid < NEXP) hist[tid] = 0;
  __syncthreads();

  if (tid < NEXP) {  // wave 0: one token per lane, serial over 64 experts
    const int t = tid;
    const float* L = &smem[t * LG_STRIDE];

    float m1 = L[0];
    int i1 = 0;
    for (int e = 1; e < NEXP; ++e) {
      float v = L[e];
      if (v > m1) { m1 = v; i1 = e; }  // strict > keeps lowest index on ties
    }
    float m2 = -3.4e38f;
    int i2 = 0;
    for (int e = 0; e < NEXP; ++e) {
      if (e == i1) continue;
      float v = L[e];
      if (v > m2) { m2 = v; i2 = e; }
    }

    float s = 0.f;
    for (int e = 0; e < NEXP; ++e) s += expf(L[e] - m1);
    float p1 = expf(L[i1] - m1) / s;
    float p2 = expf(L[i2] - m1) / s;
    float wsum = p1 + p2 + 1e-8f;
    float w1 = p1 / wsum;
    float w2 = p2 / wsum;

    float ent = 0.f;
    for (int e = 0; e < NEXP; ++e) {
      float p = expf(L[e] - m1) / s;
      ent -= p * logf(p + 1e-10f);
    }
    float lse = m1 + logf(s);

    size_t gt = (size_t)blockIdx.x * TTILE + t;
    out[OFF_IDX + gt * 2 + 0] = (float)i1;
    out[OFF_IDX + gt * 2 + 1] = (float)i2;
    out[OFF_W + gt * 2 + 0] = w1;
    out[OFF_W + gt * 2 + 1] = w2;
    out[OFF_CONF + gt] = fmaxf(w1, w2);

    atomicAdd(&hist[i1], 1u);
    atomicAdd(&hist[i2], 1u);

    float zv = lse, ev = ent;
#pragma unroll
    for (int o = 32; o > 0; o >>= 1) {
      zv += __shfl_down(zv, o);
      ev += __shfl_down(ev, o);
    }
    if (t == 0) {
      atomicAdd(&ws->z_sum, (double)zv);
      atomicAdd(&ws->ent_sum, (double)ev);
    }
  }
  __syncthreads();
  if (tid < NEXP) atomicAdd(&ws->counts[tid], hist[tid]);
}

__global__ void router_final(float* __restrict__ out, RouterWS* __restrict__ ws) {
  int e = threadIdx.x;  // 64 threads
  float c = (float)ws->counts[e];
  out[OFF_CNT + e] = c;
  float over = fmaxf(c - 1280.f, 0.f);   // capacity = int(1.25*32768/64*2)
  float ld = c / 65536.f - (1.f / 64.f);
  float so = over, sv = ld * ld;
#pragma unroll
  for (int o = 32; o > 0; o >>= 1) {
    so += __shfl_down(so, o);
    sv += __shfl_down(sv, o);
  }
  if (e == 0) {
    out[OFF_OVF] = so / 32768.f * 100.f;
    out[OFF_VAR] = sv / 64.f;
    out[OFF_ZL] = (float)(ws->z_sum / 32768.0 * 0.01);
    out[OFF_ENT] = (float)(ws->ent_sum / 32768.0);
  }
}

extern "C" void kernel_launch(void* const* d_in, const int* in_sizes, int n_in,
                              void* d_out, int out_size, void* d_ws, size_t ws_size,
                              hipStream_t stream) {
  const float* x = (const float*)d_in[0];   // hidden_states [4,8192,2048] f32
  const float* w = (const float*)d_in[1];   // gate_weight [64,2048] f32
  float* out = (float*)d_out;
  RouterWS* ws = (RouterWS*)d_ws;

  hipMemsetAsync(d_ws, 0, sizeof(RouterWS), stream);
  hipLaunchKernelGGL(router_main, dim3(NTOK / TTILE), dim3(256), 0, stream,
                     x, w, out, ws);
  hipLaunchKernelGGL(router_final, dim3(1), dim3(64), 0, stream, out, ws);
}